// Round 1
// baseline (1429.686 us; speedup 1.0000x reference)
//
#include <hip/hip_runtime.h>
#include <hip/hip_bf16.h>

typedef unsigned short u16;
typedef __attribute__((ext_vector_type(4))) unsigned short us4;
typedef __attribute__((ext_vector_type(4))) float f32x4;
typedef __attribute__((ext_vector_type(8))) __bf16 bf16x8;

#define D 4096
#define NTOK 8192
#define MAXR 64
#define BM 128
#define BN 128
#define BK 64

__device__ __forceinline__ u16 f2bf(float f) {
  union { float f; unsigned u; } v; v.f = f;
  unsigned u = v.u;
  u += 0x7fffu + ((u >> 16) & 1u);   // round-to-nearest-even
  return (u16)(u >> 16);
}
__device__ __forceinline__ float bf2f(u16 h) {
  union { unsigned u; float f; } v; v.u = ((unsigned)h) << 16;
  return v.f;
}

// ---------------- split f32 -> hi/lo bf16 ----------------
__global__ __launch_bounds__(256) void split_kernel(const float* __restrict__ in,
                                                    u16* __restrict__ hi,
                                                    u16* __restrict__ lo, int n4) {
  int idx = blockIdx.x * 256 + threadIdx.x;
  int stride = gridDim.x * 256;
  const float4* in4 = (const float4*)in;
  us4* hi4 = (us4*)hi;
  us4* lo4 = (us4*)lo;
  for (int i = idx; i < n4; i += stride) {
    float4 v = in4[i];
    us4 h, l;
    h.x = f2bf(v.x); l.x = f2bf(v.x - bf2f(h.x));
    h.y = f2bf(v.y); l.y = f2bf(v.y - bf2f(h.y));
    h.z = f2bf(v.z); l.z = f2bf(v.z - bf2f(h.z));
    h.w = f2bf(v.w); l.w = f2bf(v.w - bf2f(h.w));
    hi4[i] = h; lo4[i] = l;
  }
}

// ---------------- f32 -> bf16 (B matrix) ----------------
__global__ __launch_bounds__(256) void cvt_kernel(const float* __restrict__ in,
                                                  u16* __restrict__ outp, int n4) {
  int idx = blockIdx.x * 256 + threadIdx.x;
  int stride = gridDim.x * 256;
  const float4* in4 = (const float4*)in;
  us4* o4 = (us4*)outp;
  for (int i = idx; i < n4; i += stride) {
    float4 v = in4[i];
    us4 h;
    h.x = f2bf(v.x); h.y = f2bf(v.y); h.z = f2bf(v.z); h.w = f2bf(v.w);
    o4[i] = h;
  }
}

// ---------------- routing + masked t[N][64] (bf16) ----------------
// One block per token. 4 waves: wave w computes A rows w*16..w*16+15 plus gate row w.
__global__ __launch_bounds__(256) void route_kernel(const float* __restrict__ x,
                                                    const float* __restrict__ A,
                                                    const float* __restrict__ gw,
                                                    const float* __restrict__ gb,
                                                    u16* __restrict__ t) {
  int token = blockIdx.x;
  int tid = threadIdx.x;
  __shared__ float4 xs[D / 4];
  __shared__ float dots[MAXR];
  __shared__ float gsc[4];

  const float4* xr = (const float4*)(x + (size_t)token * D);
#pragma unroll
  for (int i = 0; i < 4; i++) xs[tid + i * 256] = xr[tid + i * 256];
  __syncthreads();

  int wid = tid >> 6, lane = tid & 63;

  // 16 A-row dots per wave
  for (int jj = 0; jj < 16; jj++) {
    int j = wid * 16 + jj;
    const float4* Ar = (const float4*)(A + (size_t)j * D);
    float s = 0.f;
#pragma unroll
    for (int it = 0; it < 16; it++) {
      float4 a = Ar[it * 64 + lane];
      float4 xv = xs[it * 64 + lane];
      s += a.x * xv.x + a.y * xv.y + a.z * xv.z + a.w * xv.w;
    }
    for (int off = 32; off; off >>= 1) s += __shfl_xor(s, off);
    if (lane == 0) dots[j] = s;
  }
  // gate row per wave
  {
    const float4* Gr = (const float4*)(gw + (size_t)wid * D);
    float s = 0.f;
#pragma unroll
    for (int it = 0; it < 16; it++) {
      float4 g = Gr[it * 64 + lane];
      float4 xv = xs[it * 64 + lane];
      s += g.x * xv.x + g.y * xv.y + g.z * xv.z + g.w * xv.w;
    }
    for (int off = 32; off; off >>= 1) s += __shfl_xor(s, off);
    if (lane == 0) gsc[wid] = s + gb[wid];
  }
  __syncthreads();

  if (tid < MAXR) {
    // argmax over 4 gate scores (softmax is monotone; top-1 weight renormalizes to 1)
    float best = gsc[0]; int k = 0;
#pragma unroll
    for (int i = 1; i < 4; i++) { float v = gsc[i]; if (v > best) { best = v; k = i; } }
    int r = 8 << k;  // RANKS = {8,16,32,64}
    float v = (tid < r) ? dots[tid] : 0.f;
    t[(size_t)token * MAXR + tid] = f2bf(v);
  }
}

// ---------------- fused GEMM ----------------
__device__ __forceinline__ void gload16(void* lds, const void* g) {
  __builtin_amdgcn_global_load_lds((const __attribute__((address_space(1))) void*)g,
                                   (__attribute__((address_space(3))) void*)lds, 16, 0, 0);
}

template <bool THREE>
__device__ __forceinline__ void compute_tile(f32x4 acc[4][4], const u16* Ah, const u16* Al,
                                             const u16* Bh, const u16* Bl, int lane, int wr,
                                             int wc) {
  int ar = lane & 15;
#pragma unroll
  for (int ks = 0; ks < 2; ks++) {
    int kc = ks * 32 + (lane >> 4) * 8;
    bf16x8 ah[4], al[4], bh[4], bl[4];
#pragma unroll
    for (int mi = 0; mi < 4; mi++) {
      int rowA = (wr * 64 + mi * 16 + ar) * BK + kc;
      ah[mi] = *(const bf16x8*)&Ah[rowA];
      if (THREE) al[mi] = *(const bf16x8*)&Al[rowA];
    }
#pragma unroll
    for (int ni = 0; ni < 4; ni++) {
      int rowB = (wc * 64 + ni * 16 + ar) * BK + kc;
      bh[ni] = *(const bf16x8*)&Bh[rowB];
      if (THREE) bl[ni] = *(const bf16x8*)&Bl[rowB];
    }
#pragma unroll
    for (int mi = 0; mi < 4; mi++)
#pragma unroll
      for (int ni = 0; ni < 4; ni++) {
        acc[mi][ni] = __builtin_amdgcn_mfma_f32_16x16x32_bf16(ah[mi], bh[ni], acc[mi][ni], 0, 0, 0);
        if (THREE) {
          acc[mi][ni] = __builtin_amdgcn_mfma_f32_16x16x32_bf16(ah[mi], bl[ni], acc[mi][ni], 0, 0, 0);
          acc[mi][ni] = __builtin_amdgcn_mfma_f32_16x16x32_bf16(al[mi], bh[ni], acc[mi][ni], 0, 0, 0);
        }
      }
  }
}

__global__ __launch_bounds__(256) void gemm_kernel(const u16* __restrict__ xh,
                                                   const u16* __restrict__ xl,
                                                   const u16* __restrict__ wh,
                                                   const u16* __restrict__ wl,
                                                   const u16* __restrict__ tb,
                                                   const u16* __restrict__ bmat,
                                                   const float* __restrict__ bias,
                                                   float* __restrict__ out) {
  __shared__ u16 Ah[BM * BK];
  __shared__ u16 Al[BM * BK];
  __shared__ u16 Bh[BN * BK];
  __shared__ u16 Bl[BN * BK];

  // XCD-aware swizzle (2048 blocks % 8 == 0 -> bijective)
  int bid = blockIdx.x;
  int cpx = gridDim.x >> 3;
  int swz = (bid & 7) * cpx + (bid >> 3);
  int bm_i = swz >> 5;  // /32 col-tiles
  int bn_i = swz & 31;
  int brow = bm_i * BM;
  int bcol = bn_i * BN;

  int tid = threadIdx.x, wid = tid >> 6, lane = tid & 63;
  int wr = wid >> 1, wc = wid & 1;

  f32x4 acc[4][4] = {};

  // staging lane geometry: each wave stages 32 rows of each tile (4 instrs x 8 rows)
  int srow = wid * 32 + (lane >> 3);     // + i*8
  int scol = (lane & 7) * 8;             // bf16 elems (16B per lane)

  const int KT = D / BK;  // 64
  for (int kt = 0; kt < KT; ++kt) {
    size_t kof = (size_t)kt * BK + scol;
#pragma unroll
    for (int i = 0; i < 4; i++) {
      int r = srow + i * 8;
      int lb = (wid * 32 + i * 8) * BK;
      gload16(&Ah[lb], xh + (size_t)(brow + r) * D + kof);
      gload16(&Al[lb], xl + (size_t)(brow + r) * D + kof);
      gload16(&Bh[lb], wh + (size_t)(bcol + r) * D + kof);
      gload16(&Bl[lb], wl + (size_t)(bcol + r) * D + kof);
    }
    __syncthreads();
    compute_tile<true>(acc, Ah, Al, Bh, Bl, lane, wr, wc);
    __syncthreads();
  }

  // LoRA correction: one extra K-tile, single-term bf16. t rows are 64 elems = 128B (same layout).
  {
#pragma unroll
    for (int i = 0; i < 4; i++) {
      int r = srow + i * 8;
      int lb = (wid * 32 + i * 8) * BK;
      gload16(&Ah[lb], tb + (size_t)(brow + r) * MAXR + scol);
      gload16(&Bh[lb], bmat + (size_t)(bcol + r) * MAXR + scol);
    }
    __syncthreads();
    compute_tile<false>(acc, Ah, Al, Bh, Bl, lane, wr, wc);
  }

  // epilogue: + bias, write fp32
#pragma unroll
  for (int ni = 0; ni < 4; ni++) {
    int col = bcol + wc * 64 + ni * 16 + (lane & 15);
    float bv = bias[col];
#pragma unroll
    for (int mi = 0; mi < 4; mi++) {
      int row0 = brow + wr * 64 + mi * 16 + (lane >> 4) * 4;
#pragma unroll
      for (int rg = 0; rg < 4; rg++)
        out[(size_t)(row0 + rg) * D + col] = acc[mi][ni][rg] + bv;
    }
  }
}

extern "C" void kernel_launch(void* const* d_in, const int* in_sizes, int n_in,
                              void* d_out, int out_size, void* d_ws, size_t ws_size,
                              hipStream_t stream) {
  const float* x  = (const float*)d_in[0];   // [4,2048,4096]
  const float* W  = (const float*)d_in[1];   // [4096,4096]
  const float* b  = (const float*)d_in[2];   // [4096]
  const float* A  = (const float*)d_in[3];   // [64,4096]
  const float* Bm = (const float*)d_in[4];   // [4096,64]
  const float* gw = (const float*)d_in[5];   // [4,4096]
  const float* gb = (const float*)d_in[6];   // [4]
  float* out = (float*)d_out;

  // workspace layout (bytes)
  const size_t sz_t  = (size_t)NTOK * MAXR * 2;        // 1 MB
  const size_t sz_bm = (size_t)D * MAXR * 2;           // 0.5 MB
  const size_t sz_x  = (size_t)NTOK * D * 2;           // 64 MB each
  const size_t sz_w  = (size_t)D * D * 2;              // 32 MB each
  const size_t need = sz_t + sz_bm + 2 * sz_x + 2 * sz_w;  // ~193.5 MB
  if (ws_size < need) return;  // fail loudly (validation will catch)

  char* p = (char*)d_ws;
  u16* t_bf = (u16*)p;            p += sz_t;
  u16* bm_bf = (u16*)p;           p += sz_bm;
  u16* xh = (u16*)p;              p += sz_x;
  u16* xl = (u16*)p;              p += sz_x;
  u16* whp = (u16*)p;             p += sz_w;
  u16* wlp = (u16*)p;             p += sz_w;

  // 1) split x and W to hi/lo bf16
  split_kernel<<<2048, 256, 0, stream>>>(x, xh, xl, NTOK * D / 4);
  split_kernel<<<2048, 256, 0, stream>>>(W, whp, wlp, D * D / 4);
  // 2) B matrix to bf16
  cvt_kernel<<<256, 256, 0, stream>>>(Bm, bm_bf, D * MAXR / 4);
  // 3) routing + masked t
  route_kernel<<<NTOK, 256, 0, stream>>>(x, A, gw, gb, t_bf);
  // 4) fused GEMM + LoRA + bias
  gemm_kernel<<<(NTOK / BM) * (D / BN), 256, 0, stream>>>(xh, xl, whp, wlp, t_bf, bm_bf, b, out);
}

// Round 5
// 1324.900 us; speedup vs baseline: 1.0791x; 1.0791x over previous
//
#include <hip/hip_runtime.h>
#include <hip/hip_bf16.h>

typedef unsigned short u16;
typedef __attribute__((ext_vector_type(4))) unsigned short us4;
typedef __attribute__((ext_vector_type(4))) float f32x4;
typedef __attribute__((ext_vector_type(8))) __bf16 bf16x8;

#define D 4096
#define NTOK 8192
#define MAXR 64
#define BM 128
#define BN 128
#define BK 64

__device__ __forceinline__ u16 f2bf(float f) {
  union { float f; unsigned u; } v; v.f = f;
  unsigned u = v.u;
  u += 0x7fffu + ((u >> 16) & 1u);   // round-to-nearest-even
  return (u16)(u >> 16);
}
__device__ __forceinline__ float bf2f(u16 h) {
  union { unsigned u; float f; } v; v.u = ((unsigned)h) << 16;
  return v.f;
}

// ---------------- split W -> hi/lo bf16 ----------------
__global__ __launch_bounds__(256) void split_kernel(const float* __restrict__ in,
                                                    u16* __restrict__ hi,
                                                    u16* __restrict__ lo, int n4) {
  int idx = blockIdx.x * 256 + threadIdx.x;
  int stride = gridDim.x * 256;
  const float4* in4 = (const float4*)in;
  us4* hi4 = (us4*)hi;
  us4* lo4 = (us4*)lo;
  for (int i = idx; i < n4; i += stride) {
    float4 v = in4[i];
    us4 h, l;
    h.x = f2bf(v.x); l.x = f2bf(v.x - bf2f(h.x));
    h.y = f2bf(v.y); l.y = f2bf(v.y - bf2f(h.y));
    h.z = f2bf(v.z); l.z = f2bf(v.z - bf2f(h.z));
    h.w = f2bf(v.w); l.w = f2bf(v.w - bf2f(h.w));
    hi4[i] = h; lo4[i] = l;
  }
}

// ---------------- f32 -> bf16 (B matrix) ----------------
__global__ __launch_bounds__(256) void cvt_kernel(const float* __restrict__ in,
                                                  u16* __restrict__ outp, int n4) {
  int idx = blockIdx.x * 256 + threadIdx.x;
  int stride = gridDim.x * 256;
  const float4* in4 = (const float4*)in;
  us4* o4 = (us4*)outp;
  for (int i = idx; i < n4; i += stride) {
    float4 v = in4[i];
    us4 h;
    h.x = f2bf(v.x); h.y = f2bf(v.y); h.z = f2bf(v.z); h.w = f2bf(v.w);
    o4[i] = h;
  }
}

// ---------------- split x -> hi/lo bf16 + gate scores ----------------
// 8 tokens per block (2 per wave, sequential). gw [4][4096] is L2-resident.
__global__ __launch_bounds__(256) void splitx_gate_kernel(const float* __restrict__ x,
                                                          const float* __restrict__ gw,
                                                          const float* __restrict__ gb,
                                                          u16* __restrict__ hi,
                                                          u16* __restrict__ lo,
                                                          float* __restrict__ scores) {
  int wid = threadIdx.x >> 6, lane = threadIdx.x & 63;
  int tok0 = blockIdx.x * 8 + wid * 2;
  const float4* gw4 = (const float4*)gw;

  for (int tt = 0; tt < 2; ++tt) {
    int tok = tok0 + tt;
    const float4* xr = (const float4*)(x + (size_t)tok * D);
    us4* hr = (us4*)(hi + (size_t)tok * D);
    us4* lr = (us4*)(lo + (size_t)tok * D);
    float g0 = 0.f, g1 = 0.f, g2 = 0.f, g3 = 0.f;
#pragma unroll
    for (int it = 0; it < 16; ++it) {
      int k4 = lane + it * 64;
      float4 v = xr[k4];
      us4 h, l;
      h.x = f2bf(v.x); l.x = f2bf(v.x - bf2f(h.x));
      h.y = f2bf(v.y); l.y = f2bf(v.y - bf2f(h.y));
      h.z = f2bf(v.z); l.z = f2bf(v.z - bf2f(h.z));
      h.w = f2bf(v.w); l.w = f2bf(v.w - bf2f(h.w));
      hr[k4] = h; lr[k4] = l;
      float4 w0 = gw4[0 * 1024 + k4];
      float4 w1 = gw4[1 * 1024 + k4];
      float4 w2 = gw4[2 * 1024 + k4];
      float4 w3 = gw4[3 * 1024 + k4];
      g0 += v.x * w0.x + v.y * w0.y + v.z * w0.z + v.w * w0.w;
      g1 += v.x * w1.x + v.y * w1.y + v.z * w1.z + v.w * w1.w;
      g2 += v.x * w2.x + v.y * w2.y + v.z * w2.z + v.w * w2.w;
      g3 += v.x * w3.x + v.y * w3.y + v.z * w3.z + v.w * w3.w;
    }
#pragma unroll
    for (int off = 32; off; off >>= 1) {
      g0 += __shfl_xor(g0, off);
      g1 += __shfl_xor(g1, off);
      g2 += __shfl_xor(g2, off);
      g3 += __shfl_xor(g3, off);
    }
    if (lane == 0) {
      float* s = scores + (size_t)tok * 4;
      s[0] = g0 + gb[0]; s[1] = g1 + gb[1]; s[2] = g2 + gb[2]; s[3] = g3 + gb[3];
    }
  }
}

// ---------------- t = masked (x @ A^T) as tiled f32 GEMM ----------------
// 16 tokens/block, 256 threads. Wave w owns A-rows w*16..w*16+15.
// Lane (lr=lane&15, tg=lane>>4): row = w*16+lr, tokens tg*4..tg*4+3, full-K acc.
#define KC 512
#define XS_STRIDE (KC + 4)
__global__ __launch_bounds__(256) void tgemm_kernel(const float* __restrict__ x,
                                                    const float* __restrict__ A,
                                                    const float* __restrict__ scores,
                                                    u16* __restrict__ t) {
  __shared__ float xs[16 * XS_STRIDE];
  int tid = threadIdx.x;
  int wid = tid >> 6, lane = tid & 63;
  int lr = lane & 15, tg = lane >> 4;
  int tb0 = blockIdx.x * 16;
  int row = wid * 16 + lr;

  float acc[4] = {0.f, 0.f, 0.f, 0.f};
  const float4* Ar = (const float4*)(A + (size_t)row * D);

  for (int kb = 0; kb < D / KC; ++kb) {
    // stage x[16][KC]: 16 rows x 128 float4 = 2048 slots, 256 threads -> 8 iters
#pragma unroll
    for (int i = 0; i < 8; ++i) {
      int idx = tid + i * 256;             // 0..2047 float4 slots
      int tk = idx >> 7;                   // /128 float4-per-row -> 0..15
      int c4 = idx & 127;
      float4 v = *((const float4*)(x + (size_t)(tb0 + tk) * D + kb * KC) + c4);
      *(float4*)&xs[tk * XS_STRIDE + c4 * 4] = v;
    }
    __syncthreads();

    const float4* Ak = Ar + kb * (KC / 4);
#pragma unroll 4
    for (int k4 = 0; k4 < KC / 4; ++k4) {
      float4 a4 = Ak[k4];
#pragma unroll
      for (int j = 0; j < 4; ++j) {
        float4 x4 = *(const float4*)&xs[(tg * 4 + j) * XS_STRIDE + k4 * 4];
        acc[j] += a4.x * x4.x + a4.y * x4.y + a4.z * x4.z + a4.w * x4.w;
      }
    }
    __syncthreads();
  }

  // epilogue: argmax gate -> rank mask -> bf16 store
#pragma unroll
  for (int j = 0; j < 4; ++j) {
    int tok = tb0 + tg * 4 + j;
    const float* s = scores + (size_t)tok * 4;
    float best = s[0]; int k = 0;
#pragma unroll
    for (int i = 1; i < 4; ++i) { float v = s[i]; if (v > best) { best = v; k = i; } }
    int r = 8 << k;  // RANKS = {8,16,32,64}
    float v = (row < r) ? acc[j] : 0.f;
    t[(size_t)tok * MAXR + row] = f2bf(v);
  }
}

// ---------------- fused GEMM ----------------
__device__ __forceinline__ void gload16(void* lds, const void* g) {
  __builtin_amdgcn_global_load_lds((const __attribute__((address_space(1))) void*)g,
                                   (__attribute__((address_space(3))) void*)lds, 16, 0, 0);
}

// LDS tiles are [rows][64] bf16 = 128B row stride. Physical chunk p (16B) of row r
// holds global chunk p ^ (r&7); reads XOR the chunk index with (row&7).
template <bool THREE>
__device__ __forceinline__ void compute_tile(f32x4 acc[4][4], const u16* Ah, const u16* Al,
                                             const u16* Bh, const u16* Bl, int lane, int wr,
                                             int wc) {
  int ar = lane & 15;
  int swz = (lane & 7) << 3;  // row&7 == ar&7 == lane&7 for all fragment rows
#pragma unroll
  for (int ks = 0; ks < 2; ks++) {
    int kc = (ks * 32 + (lane >> 4) * 8) ^ swz;
    bf16x8 ah[4], al[4], bh[4], bl[4];
#pragma unroll
    for (int mi = 0; mi < 4; mi++) {
      int rowA = (wr * 64 + mi * 16 + ar) * BK + kc;
      ah[mi] = *(const bf16x8*)&Ah[rowA];
      if (THREE) al[mi] = *(const bf16x8*)&Al[rowA];
    }
#pragma unroll
    for (int ni = 0; ni < 4; ni++) {
      int rowB = (wc * 64 + ni * 16 + ar) * BK + kc;
      bh[ni] = *(const bf16x8*)&Bh[rowB];
      if (THREE) bl[ni] = *(const bf16x8*)&Bl[rowB];
    }
#pragma unroll
    for (int mi = 0; mi < 4; mi++)
#pragma unroll
      for (int ni = 0; ni < 4; ni++) {
        acc[mi][ni] = __builtin_amdgcn_mfma_f32_16x16x32_bf16(ah[mi], bh[ni], acc[mi][ni], 0, 0, 0);
        if (THREE) {
          acc[mi][ni] = __builtin_amdgcn_mfma_f32_16x16x32_bf16(ah[mi], bl[ni], acc[mi][ni], 0, 0, 0);
          acc[mi][ni] = __builtin_amdgcn_mfma_f32_16x16x32_bf16(al[mi], bh[ni], acc[mi][ni], 0, 0, 0);
        }
      }
  }
}

__global__ __launch_bounds__(256) void gemm_kernel(const u16* __restrict__ xh,
                                                   const u16* __restrict__ xl,
                                                   const u16* __restrict__ wh,
                                                   const u16* __restrict__ wl,
                                                   const u16* __restrict__ tb,
                                                   const u16* __restrict__ bmat,
                                                   const float* __restrict__ bias,
                                                   float* __restrict__ out) {
  __shared__ u16 Ah[BM * BK];
  __shared__ u16 Al[BM * BK];
  __shared__ u16 Bh[BN * BK];
  __shared__ u16 Bl[BN * BK];

  // XCD-aware swizzle (2048 blocks % 8 == 0 -> bijective)
  int bid = blockIdx.x;
  int cpx = gridDim.x >> 3;
  int swzb = (bid & 7) * cpx + (bid >> 3);
  int bm_i = swzb >> 5;
  int bn_i = swzb & 31;
  int brow = bm_i * BM;
  int bcol = bn_i * BN;

  int tid = threadIdx.x, wid = tid >> 6, lane = tid & 63;
  int wr = wid >> 1, wc = wid & 1;

  f32x4 acc[4][4] = {};

  // staging: lane l writes LDS linear slot (row=l>>3, chunk=l&7); source chunk
  // is pre-swizzled so physical chunk p holds global chunk p ^ (row&7).
  int srow = wid * 32 + (lane >> 3);                      // + i*8
  int scol = ((lane & 7) ^ ((lane >> 3) & 7)) * 8;        // bf16 elems (16B/lane)

  const int KT = D / BK;  // 64
  for (int kt = 0; kt < KT; ++kt) {
    size_t kof = (size_t)kt * BK + scol;
#pragma unroll
    for (int i = 0; i < 4; i++) {
      int r = srow + i * 8;
      int lb = (wid * 32 + i * 8) * BK;
      gload16(&Ah[lb], xh + (size_t)(brow + r) * D + kof);
      gload16(&Al[lb], xl + (size_t)(brow + r) * D + kof);
      gload16(&Bh[lb], wh + (size_t)(bcol + r) * D + kof);
      gload16(&Bl[lb], wl + (size_t)(bcol + r) * D + kof);
    }
    __syncthreads();
    compute_tile<true>(acc, Ah, Al, Bh, Bl, lane, wr, wc);
    __syncthreads();
  }

  // LoRA correction: one extra K-tile, single-term bf16 (t rows = 64 elems = 128B).
  {
#pragma unroll
    for (int i = 0; i < 4; i++) {
      int r = srow + i * 8;
      int lb = (wid * 32 + i * 8) * BK;
      gload16(&Ah[lb], tb + (size_t)(brow + r) * MAXR + scol);
      gload16(&Bh[lb], bmat + (size_t)(bcol + r) * MAXR + scol);
    }
    __syncthreads();
    compute_tile<false>(acc, Ah, Al, Bh, Bl, lane, wr, wc);
  }

  // epilogue: + bias, write fp32
#pragma unroll
  for (int ni = 0; ni < 4; ni++) {
    int col = bcol + wc * 64 + ni * 16 + (lane & 15);
    float bv = bias[col];
#pragma unroll
    for (int mi = 0; mi < 4; mi++) {
      int row0 = brow + wr * 64 + mi * 16 + (lane >> 4) * 4;
#pragma unroll
      for (int rg = 0; rg < 4; rg++)
        out[(size_t)(row0 + rg) * D + col] = acc[mi][ni][rg] + bv;
    }
  }
}

extern "C" void kernel_launch(void* const* d_in, const int* in_sizes, int n_in,
                              void* d_out, int out_size, void* d_ws, size_t ws_size,
                              hipStream_t stream) {
  const float* x  = (const float*)d_in[0];   // [4,2048,4096]
  const float* W  = (const float*)d_in[1];   // [4096,4096]
  const float* b  = (const float*)d_in[2];   // [4096]
  const float* A  = (const float*)d_in[3];   // [64,4096]
  const float* Bm = (const float*)d_in[4];   // [4096,64]
  const float* gw = (const float*)d_in[5];   // [4,4096]
  const float* gb = (const float*)d_in[6];   // [4]
  float* out = (float*)d_out;

  // workspace layout (bytes)
  const size_t sz_t  = (size_t)NTOK * MAXR * 2;        // 1 MB
  const size_t sz_bm = (size_t)D * MAXR * 2;           // 0.5 MB
  const size_t sz_sc = (size_t)NTOK * 4 * 4;           // 128 KB
  const size_t sz_x  = (size_t)NTOK * D * 2;           // 64 MB each
  const size_t sz_w  = (size_t)D * D * 2;              // 32 MB each
  const size_t need = sz_t + sz_bm + sz_sc + 2 * sz_x + 2 * sz_w;
  if (ws_size < need) return;  // fail loudly (validation will catch)

  char* p = (char*)d_ws;
  u16* t_bf = (u16*)p;            p += sz_t;
  u16* bm_bf = (u16*)p;           p += sz_bm;
  float* scores = (float*)p;      p += sz_sc;
  u16* xh = (u16*)p;              p += sz_x;
  u16* xl = (u16*)p;              p += sz_x;
  u16* whp = (u16*)p;             p += sz_w;
  u16* wlp = (u16*)p;             p += sz_w;

  // 1) split x (+ gate scores) and W to hi/lo bf16
  splitx_gate_kernel<<<NTOK / 8, 256, 0, stream>>>(x, gw, gb, xh, xl, scores);
  split_kernel<<<2048, 256, 0, stream>>>(W, whp, wlp, D * D / 4);
  // 2) B matrix to bf16
  cvt_kernel<<<256, 256, 0, stream>>>(Bm, bm_bf, D * MAXR / 4);
  // 3) t = masked (x @ A^T), routing fused in epilogue
  tgemm_kernel<<<NTOK / 16, 256, 0, stream>>>(x, A, scores, t_bf);
  // 4) fused GEMM + LoRA + bias
  gemm_kernel<<<(NTOK / BM) * (D / BN), 256, 0, stream>>>(xh, xl, whp, wlp, t_bf, bm_bf, b, out);
}

// Round 6
// 914.623 us; speedup vs baseline: 1.5631x; 1.4486x over previous
//
#include <hip/hip_runtime.h>
#include <hip/hip_bf16.h>

typedef unsigned short u16;
typedef __attribute__((ext_vector_type(4))) unsigned short us4;
typedef __attribute__((ext_vector_type(4))) float f32x4;
typedef __attribute__((ext_vector_type(8))) _Float16 f16x8;

#define D 4096
#define NTOK 8192
#define MAXR 64
#define BM 128
#define BN 128
#define BK 64

__device__ __forceinline__ u16 f2h(float f) {
  _Float16 h = (_Float16)f;   // v_cvt_f16_f32, RNE
  union { _Float16 h; u16 u; } v; v.h = h;
  return v.u;
}

// ---------------- f32 -> f16 (W and B matrices) ----------------
__global__ __launch_bounds__(256) void cvt_kernel(const float* __restrict__ in,
                                                  u16* __restrict__ outp, int n4) {
  int idx = blockIdx.x * 256 + threadIdx.x;
  int stride = gridDim.x * 256;
  const float4* in4 = (const float4*)in;
  us4* o4 = (us4*)outp;
  for (int i = idx; i < n4; i += stride) {
    float4 v = in4[i];
    us4 h;
    h.x = f2h(v.x); h.y = f2h(v.y); h.z = f2h(v.z); h.w = f2h(v.w);
    o4[i] = h;
  }
}

// ---------------- x -> f16 + gate scores ----------------
// 8 tokens per block (2 per wave, sequential). gw [4][4096] is L2-resident.
__global__ __launch_bounds__(256) void cvtx_gate_kernel(const float* __restrict__ x,
                                                        const float* __restrict__ gw,
                                                        const float* __restrict__ gb,
                                                        u16* __restrict__ xf,
                                                        float* __restrict__ scores) {
  int wid = threadIdx.x >> 6, lane = threadIdx.x & 63;
  int tok0 = blockIdx.x * 8 + wid * 2;
  const float4* gw4 = (const float4*)gw;

  for (int tt = 0; tt < 2; ++tt) {
    int tok = tok0 + tt;
    const float4* xr = (const float4*)(x + (size_t)tok * D);
    us4* hr = (us4*)(xf + (size_t)tok * D);
    float g0 = 0.f, g1 = 0.f, g2 = 0.f, g3 = 0.f;
#pragma unroll
    for (int it = 0; it < 16; ++it) {
      int k4 = lane + it * 64;
      float4 v = xr[k4];
      us4 h;
      h.x = f2h(v.x); h.y = f2h(v.y); h.z = f2h(v.z); h.w = f2h(v.w);
      hr[k4] = h;
      float4 w0 = gw4[0 * 1024 + k4];
      float4 w1 = gw4[1 * 1024 + k4];
      float4 w2 = gw4[2 * 1024 + k4];
      float4 w3 = gw4[3 * 1024 + k4];
      g0 += v.x * w0.x + v.y * w0.y + v.z * w0.z + v.w * w0.w;
      g1 += v.x * w1.x + v.y * w1.y + v.z * w1.z + v.w * w1.w;
      g2 += v.x * w2.x + v.y * w2.y + v.z * w2.z + v.w * w2.w;
      g3 += v.x * w3.x + v.y * w3.y + v.z * w3.z + v.w * w3.w;
    }
#pragma unroll
    for (int off = 32; off; off >>= 1) {
      g0 += __shfl_xor(g0, off);
      g1 += __shfl_xor(g1, off);
      g2 += __shfl_xor(g2, off);
      g3 += __shfl_xor(g3, off);
    }
    if (lane == 0) {
      float* s = scores + (size_t)tok * 4;
      s[0] = g0 + gb[0]; s[1] = g1 + gb[1]; s[2] = g2 + gb[2]; s[3] = g3 + gb[3];
    }
  }
}

// ---------------- t = masked (x @ A^T) as tiled f32 GEMM ----------------
// 16 tokens/block, 256 threads. Wave w owns A-rows w*16..w*16+15.
// Lane (lr=lane&15, tg=lane>>4): row = w*16+lr, tokens tg*4..tg*4+3, full-K acc.
#define KC 512
#define XS_STRIDE (KC + 4)
__global__ __launch_bounds__(256) void tgemm_kernel(const float* __restrict__ x,
                                                    const float* __restrict__ A,
                                                    const float* __restrict__ scores,
                                                    u16* __restrict__ t) {
  __shared__ float xs[16 * XS_STRIDE];
  int tid = threadIdx.x;
  int wid = tid >> 6, lane = tid & 63;
  int lr = lane & 15, tg = lane >> 4;
  int tb0 = blockIdx.x * 16;
  int row = wid * 16 + lr;

  float acc[4] = {0.f, 0.f, 0.f, 0.f};
  const float4* Ar = (const float4*)(A + (size_t)row * D);

  for (int kb = 0; kb < D / KC; ++kb) {
    // stage x[16][KC]: 16 rows x 128 float4 = 2048 slots, 256 threads -> 8 iters
#pragma unroll
    for (int i = 0; i < 8; ++i) {
      int idx = tid + i * 256;             // 0..2047 float4 slots
      int tk = idx >> 7;                   // /128 float4-per-row -> 0..15
      int c4 = idx & 127;
      float4 v = *((const float4*)(x + (size_t)(tb0 + tk) * D + kb * KC) + c4);
      *(float4*)&xs[tk * XS_STRIDE + c4 * 4] = v;
    }
    __syncthreads();

    const float4* Ak = Ar + kb * (KC / 4);
#pragma unroll 4
    for (int k4 = 0; k4 < KC / 4; ++k4) {
      float4 a4 = Ak[k4];
#pragma unroll
      for (int j = 0; j < 4; ++j) {
        float4 x4 = *(const float4*)&xs[(tg * 4 + j) * XS_STRIDE + k4 * 4];
        acc[j] += a4.x * x4.x + a4.y * x4.y + a4.z * x4.z + a4.w * x4.w;
      }
    }
    __syncthreads();
  }

  // epilogue: argmax gate -> rank mask -> f16 store
#pragma unroll
  for (int j = 0; j < 4; ++j) {
    int tok = tb0 + tg * 4 + j;
    const float* s = scores + (size_t)tok * 4;
    float best = s[0]; int k = 0;
#pragma unroll
    for (int i = 1; i < 4; ++i) { float v = s[i]; if (v > best) { best = v; k = i; } }
    int r = 8 << k;  // RANKS = {8,16,32,64}
    float v = (row < r) ? acc[j] : 0.f;
    t[(size_t)tok * MAXR + row] = f2h(v);
  }
}

// ---------------- fused GEMM (single-term f16) ----------------
__device__ __forceinline__ void gload16(void* lds, const void* g) {
  __builtin_amdgcn_global_load_lds((const __attribute__((address_space(1))) void*)g,
                                   (__attribute__((address_space(3))) void*)lds, 16, 0, 0);
}

// LDS tiles are [rows][64] f16 = 128B row stride. Physical chunk p (16B) of row r
// holds global chunk p ^ (r&7); reads XOR the chunk index with (row&7).
__device__ __forceinline__ void compute_tile(f32x4 acc[4][4], const u16* Af, const u16* Bf,
                                             int lane, int wr, int wc) {
  int ar = lane & 15;
  int swz = (lane & 7) << 3;  // row&7 == ar&7 == lane&7 for all fragment rows
#pragma unroll
  for (int ks = 0; ks < 2; ks++) {
    int kc = (ks * 32 + (lane >> 4) * 8) ^ swz;
    f16x8 a[4], b[4];
#pragma unroll
    for (int mi = 0; mi < 4; mi++)
      a[mi] = *(const f16x8*)&Af[(wr * 64 + mi * 16 + ar) * BK + kc];
#pragma unroll
    for (int ni = 0; ni < 4; ni++)
      b[ni] = *(const f16x8*)&Bf[(wc * 64 + ni * 16 + ar) * BK + kc];
#pragma unroll
    for (int mi = 0; mi < 4; mi++)
#pragma unroll
      for (int ni = 0; ni < 4; ni++)
        acc[mi][ni] = __builtin_amdgcn_mfma_f32_16x16x32_f16(a[mi], b[ni], acc[mi][ni], 0, 0, 0);
  }
}

__global__ __launch_bounds__(256) void gemm_kernel(const u16* __restrict__ xf,
                                                   const u16* __restrict__ wf,
                                                   const u16* __restrict__ tb,
                                                   const u16* __restrict__ bmat,
                                                   const float* __restrict__ bias,
                                                   float* __restrict__ out) {
  __shared__ u16 Af[BM * BK];
  __shared__ u16 Bf[BN * BK];

  // XCD-aware swizzle (2048 blocks % 8 == 0 -> bijective)
  int bid = blockIdx.x;
  int cpx = gridDim.x >> 3;
  int swzb = (bid & 7) * cpx + (bid >> 3);
  int bm_i = swzb >> 5;
  int bn_i = swzb & 31;
  int brow = bm_i * BM;
  int bcol = bn_i * BN;

  int tid = threadIdx.x, wid = tid >> 6, lane = tid & 63;
  int wr = wid >> 1, wc = wid & 1;

  f32x4 acc[4][4] = {};

  // staging: lane l writes LDS linear slot (row=l>>3, chunk=l&7); source chunk
  // is pre-swizzled so physical chunk p holds global chunk p ^ (row&7).
  int srow = wid * 32 + (lane >> 3);                      // + i*8
  int scol = ((lane & 7) ^ ((lane >> 3) & 7)) * 8;        // f16 elems (16B/lane)

  const int KT = D / BK;  // 64
  for (int kt = 0; kt < KT; ++kt) {
    size_t kof = (size_t)kt * BK + scol;
#pragma unroll
    for (int i = 0; i < 4; i++) {
      int r = srow + i * 8;
      int lb = (wid * 32 + i * 8) * BK;
      gload16(&Af[lb], xf + (size_t)(brow + r) * D + kof);
      gload16(&Bf[lb], wf + (size_t)(bcol + r) * D + kof);
    }
    __syncthreads();
    compute_tile(acc, Af, Bf, lane, wr, wc);
    __syncthreads();
  }

  // LoRA correction: one extra K-tile (t rows = 64 elems = 128B, same geometry).
  {
#pragma unroll
    for (int i = 0; i < 4; i++) {
      int r = srow + i * 8;
      int lb = (wid * 32 + i * 8) * BK;
      gload16(&Af[lb], tb + (size_t)(brow + r) * MAXR + scol);
      gload16(&Bf[lb], bmat + (size_t)(bcol + r) * MAXR + scol);
    }
    __syncthreads();
    compute_tile(acc, Af, Bf, lane, wr, wc);
  }

  // epilogue: + bias, write fp32
#pragma unroll
  for (int ni = 0; ni < 4; ni++) {
    int col = bcol + wc * 64 + ni * 16 + (lane & 15);
    float bv = bias[col];
#pragma unroll
    for (int mi = 0; mi < 4; mi++) {
      int row0 = brow + wr * 64 + mi * 16 + (lane >> 4) * 4;
#pragma unroll
      for (int rg = 0; rg < 4; rg++)
        out[(size_t)(row0 + rg) * D + col] = acc[mi][ni][rg] + bv;
    }
  }
}

extern "C" void kernel_launch(void* const* d_in, const int* in_sizes, int n_in,
                              void* d_out, int out_size, void* d_ws, size_t ws_size,
                              hipStream_t stream) {
  const float* x  = (const float*)d_in[0];   // [4,2048,4096]
  const float* W  = (const float*)d_in[1];   // [4096,4096]
  const float* b  = (const float*)d_in[2];   // [4096]
  const float* A  = (const float*)d_in[3];   // [64,4096]
  const float* Bm = (const float*)d_in[4];   // [4096,64]
  const float* gw = (const float*)d_in[5];   // [4,4096]
  const float* gb = (const float*)d_in[6];   // [4]
  float* out = (float*)d_out;

  // workspace layout (bytes)
  const size_t sz_t  = (size_t)NTOK * MAXR * 2;        // 1 MB
  const size_t sz_bm = (size_t)D * MAXR * 2;           // 0.5 MB
  const size_t sz_sc = (size_t)NTOK * 4 * 4;           // 128 KB
  const size_t sz_x  = (size_t)NTOK * D * 2;           // 64 MB
  const size_t sz_w  = (size_t)D * D * 2;              // 32 MB
  const size_t need = sz_t + sz_bm + sz_sc + sz_x + sz_w;  // ~98 MB
  if (ws_size < need) return;  // fail loudly (validation will catch)

  char* p = (char*)d_ws;
  u16* t_f16 = (u16*)p;           p += sz_t;
  u16* bm_f16 = (u16*)p;          p += sz_bm;
  float* scores = (float*)p;      p += sz_sc;
  u16* xf = (u16*)p;              p += sz_x;
  u16* wfp = (u16*)p;             p += sz_w;

  // 1) x -> f16 (+ gate scores); W -> f16
  cvtx_gate_kernel<<<NTOK / 8, 256, 0, stream>>>(x, gw, gb, xf, scores);
  cvt_kernel<<<2048, 256, 0, stream>>>(W, wfp, D * D / 4);
  // 2) B matrix to f16
  cvt_kernel<<<256, 256, 0, stream>>>(Bm, bm_f16, D * MAXR / 4);
  // 3) t = masked (x @ A^T), routing fused in epilogue
  tgemm_kernel<<<NTOK / 16, 256, 0, stream>>>(x, A, scores, t_f16);
  // 4) fused GEMM + LoRA + bias (single-term f16 MFMA)
  gemm_kernel<<<(NTOK / BM) * (D / BN), 256, 0, stream>>>(xf, wfp, t_f16, bm_f16, b, out);
}